// Round 3
// baseline (164.510 us; speedup 1.0000x reference)
//
#include <hip/hip_runtime.h>

#define RNK 32
#define VOC 32000
#define BSZ 512
#define SEQ 24

#define CHAIN_BLOCKS 128          // 4 rows/block (1 row per 64-lane wave)
#define REDUCE_BLOCKS 4000        // 32 r-slabs x 125 chunks

// ---------------------------------------------------------------------------
// Fused kernel.
//  - Blocks [0, CHAIN_BLOCKS): selected-token chain (latency-bound), depth-4
//    register prefetch of the gathered 32x32 matrices.
//  - Blocks [CHAIN_BLOCKS, ...): stream core to build gm[r][s] = sum_v core.
//    The LAST reduce block to finish (atomic counter) also computes z from gm
//    in-kernel, eliminating the trailing 1-wave kernel + launch gap.
// ---------------------------------------------------------------------------
__global__ __launch_bounds__(256) void fused_kernel(const float* __restrict__ core,
                                                    const int* __restrict__ y,
                                                    const float* __restrict__ alpha,
                                                    const float* __restrict__ beta,
                                                    float* __restrict__ out,
                                                    float* __restrict__ gm,
                                                    unsigned* __restrict__ counter) {
    if (blockIdx.x < CHAIN_BLOCKS) {
        // ---------------- chain role: p_tilde[row] ----------------
        const int tid  = threadIdx.x;
        const int lane = tid & 63;
        const int s    = lane & 31;
        const int half = lane >> 5;           // 0: rows 0..15, 1: rows 16..31
        const int row  = blockIdx.x * 4 + (tid >> 6);
        const size_t strideR = (size_t)VOC * RNK;     // r-row stride in core
        const size_t halfOff = (size_t)half * 16 * strideR;

        int ytok = (lane < SEQ) ? y[row * SEQ + lane] : 0;

        float state = alpha[s];               // replicated in both halves

        float buf[5][16];                     // depth-4 prefetch pipeline

#define LOADM(SLOT, T)                                                         \
        {                                                                      \
            const int tok = __shfl(ytok, (T), 64);                             \
            const float* mb = core + (size_t)tok * RNK + s + halfOff;          \
            _Pragma("unroll")                                                  \
            for (int i = 0; i < 16; ++i) buf[SLOT][i] = mb[(size_t)i * strideR]; \
        }

        LOADM(0, 0) LOADM(1, 1) LOADM(2, 2) LOADM(3, 3)

        #pragma unroll
        for (int t = 0; t < SEQ; ++t) {       // full unroll -> static buf indices
            if (t + 4 < SEQ) LOADM((t + 4) % 5, t + 4)

            // partial dot over this half's 16 rows; 4-way split accumulator
            float a0 = 0.f, a1 = 0.f, a2 = 0.f, a3 = 0.f;
            #pragma unroll
            for (int i = 0; i < 16; i += 4) {
                a0 = fmaf(__shfl(state, half * 16 + i + 0, 64), buf[t % 5][i + 0], a0);
                a1 = fmaf(__shfl(state, half * 16 + i + 1, 64), buf[t % 5][i + 1], a1);
                a2 = fmaf(__shfl(state, half * 16 + i + 2, 64), buf[t % 5][i + 2], a2);
                a3 = fmaf(__shfl(state, half * 16 + i + 3, 64), buf[t % 5][i + 3], a3);
            }
            const float acc = (a0 + a1) + (a2 + a3);
            state = acc + __shfl_xor(acc, 32, 64);   // combine halves, re-replicate
        }
#undef LOADM

        float p = state * beta[s];
        #pragma unroll
        for (int m = 16; m >= 1; m >>= 1) p += __shfl_xor(p, m, 64); // within-half
        if (lane == 0) out[row] = p;
    } else {
        // ---------------- reduce role ----------------
        const int bid   = blockIdx.x - CHAIN_BLOCKS;
        const int r     = bid & 31;
        const int chunk = bid >> 5;           // 0..124
        const int tid   = threadIdx.x;

        const float4* slab = (const float4*)(core + (size_t)r * VOC * RNK);
        const int base = chunk * 2048 + tid;  // float4 index

        float a0 = 0.f, a1 = 0.f, a2 = 0.f, a3 = 0.f;
        #pragma unroll
        for (int i = 0; i < 8; ++i) {
            float4 v = slab[base + i * 256];
            a0 += v.x; a1 += v.y; a2 += v.z; a3 += v.w;
        }

        __shared__ float ml[RNK];
        __shared__ int isLast;
        if (tid < RNK) ml[tid] = 0.f;
        __syncthreads();

        const int s0 = (tid & 7) * 4;         // (tid*4) % 32, loop-invariant phase
        atomicAdd(&ml[s0 + 0], a0);
        atomicAdd(&ml[s0 + 1], a1);
        atomicAdd(&ml[s0 + 2], a2);
        atomicAdd(&ml[s0 + 3], a3);
        __syncthreads();

        if (tid < RNK) atomicAdd(&gm[r * RNK + tid], ml[tid]);

        // -------- last-block-out computes z in-kernel --------
        __syncthreads();
        if (tid == 0) {
            __threadfence();                  // gm adds visible before counter bump
            unsigned old = atomicAdd(counter, 1u);
            isLast = (old == REDUCE_BLOCKS - 1);
        }
        __syncthreads();

        if (isLast && tid < 64) {
            __threadfence();
            const int lane = tid;
            const int s    = lane & 31;
            const int half = lane >> 5;

            float col[16];                    // this lane's half-column of m
            #pragma unroll
            for (int i = 0; i < 16; ++i)
                col[i] = __hip_atomic_load(&gm[(half * 16 + i) * RNK + s],
                                           __ATOMIC_RELAXED, __HIP_MEMORY_SCOPE_AGENT);

            float v = alpha[s];
            #pragma unroll
            for (int t = 0; t < SEQ; ++t) {
                float b0 = 0.f, b1 = 0.f, b2 = 0.f, b3 = 0.f;
                #pragma unroll
                for (int i = 0; i < 16; i += 4) {
                    b0 = fmaf(__shfl(v, half * 16 + i + 0, 64), col[i + 0], b0);
                    b1 = fmaf(__shfl(v, half * 16 + i + 1, 64), col[i + 1], b1);
                    b2 = fmaf(__shfl(v, half * 16 + i + 2, 64), col[i + 2], b2);
                    b3 = fmaf(__shfl(v, half * 16 + i + 3, 64), col[i + 3], b3);
                }
                const float acc = (b0 + b1) + (b2 + b3);
                v = acc + __shfl_xor(acc, 32, 64);
            }
            float z = v * beta[s];
            #pragma unroll
            for (int m = 16; m >= 1; m >>= 1) z += __shfl_xor(z, m, 64);
            if (lane == 0) out[BSZ] = z * (float)BSZ;
        }
    }
}

extern "C" void kernel_launch(void* const* d_in, const int* in_sizes, int n_in,
                              void* d_out, int out_size, void* d_ws, size_t ws_size,
                              hipStream_t stream) {
    const int*   y     = (const int*)d_in[0];
    const float* alpha = (const float*)d_in[1];
    const float* beta  = (const float*)d_in[2];
    const float* core  = (const float*)d_in[3];
    float* out = (float*)d_out;
    float* gm  = (float*)d_ws;                          // 1024 floats
    unsigned* counter = (unsigned*)(gm + RNK * RNK);    // 1 uint after gm

    hipMemsetAsync(d_ws, 0, RNK * RNK * sizeof(float) + sizeof(unsigned), stream);
    fused_kernel<<<CHAIN_BLOCKS + REDUCE_BLOCKS, 256, 0, stream>>>(
        core, y, alpha, beta, out, gm, counter);
}

// Round 4
// 48.399 us; speedup vs baseline: 3.3991x; 3.3991x over previous
//
#include <hip/hip_runtime.h>

#define RNK 32
#define VOC 32000
#define BSZ 512
#define SEQ 24

#define CHAIN_BLOCKS 128          // 4 rows/block (1 row per 64-lane wave)
#define REDUCE_BLOCKS 4000        // 32 r-slabs x 125 chunks

typedef const __attribute__((address_space(1))) void* as1_cvp;
typedef __attribute__((address_space(3))) void* as3_vp;

// Issue one 32x32 fp32 token matrix (4 KB) global->LDS as 4 x (64 lanes x 16B).
// LDS dest is wave-uniform base + lane*16 (linear [r][s] layout); global source
// is per-lane: row r = j*8 + lane/8 (stride VOC*RNK floats), cols (lane%8)*4..+3.
__device__ __forceinline__ void issue_matrix_load(const float* __restrict__ src_tok, // core + tok*RNK
                                                  float* lds_base, int lane) {
    const int r  = lane >> 3;
    const int c0 = (lane & 7) * 4;
    #pragma unroll
    for (int j = 0; j < 4; ++j) {
        const float* src = src_tok + (size_t)(j * 8 + r) * ((size_t)VOC * RNK) + c0;
        __builtin_amdgcn_global_load_lds((as1_cvp)src, (as3_vp)(lds_base + j * 256), 16, 0, 0);
    }
}

// ---------------------------------------------------------------------------
// Fused kernel.
//  - Blocks [0, CHAIN_BLOCKS): selected-token chain, matrices staged in LDS
//    (3 rotating 4KB buffers per wave) via global_load_lds + counted vmcnt.
//    Chain VGPR footprint is tiny -> no scratch spill (the R3 killer).
//  - Blocks [CHAIN_BLOCKS, ...): stream core to build gm[r][s] = sum_v core.
// ---------------------------------------------------------------------------
__global__ __launch_bounds__(256) void fused_kernel(const float* __restrict__ core,
                                                    const int* __restrict__ y,
                                                    const float* __restrict__ alpha,
                                                    const float* __restrict__ beta,
                                                    float* __restrict__ out,
                                                    float* __restrict__ gm) {
    __shared__ float shmem[4 * 3 * 1024 + RNK];   // 48KB chain buffers + reduce's ml

    if (blockIdx.x < CHAIN_BLOCKS) {
        // ---------------- chain role: p_tilde[row] ----------------
        const int tid  = threadIdx.x;
        const int lane = tid & 63;
        const int w    = tid >> 6;            // wave id 0..3, one row per wave
        const int s    = lane & 31;
        const int half = lane >> 5;           // 0: rows 0..15, 1: rows 16..31
        const int row  = blockIdx.x * 4 + w;

        float* mybuf = shmem + w * 3072;      // 3 x 1024 floats, private to this wave

        int   ytok  = (lane < SEQ) ? y[row * SEQ + lane] : 0;
        float state = alpha[s];               // replicated in both halves
        float betav = beta[s];

        // Drain all scalar loads so vmcnt counts ONLY our gl_lds ops below.
        asm volatile("s_waitcnt vmcnt(0)" ::: "memory");

        // prologue: t=0 and t=1 in flight (8 outstanding)
        {
            const int tok = __shfl(ytok, 0, 64);
            issue_matrix_load(core + (size_t)tok * RNK, mybuf + 0 * 1024, lane);
        }
        {
            const int tok = __shfl(ytok, 1, 64);
            issue_matrix_load(core + (size_t)tok * RNK, mybuf + 1 * 1024, lane);
        }

        #pragma unroll
        for (int t = 0; t < SEQ; ++t) {       // fully unrolled -> waits are literals
            // entering: loads for t (4) and t+1 (4) outstanding
            if (t < SEQ - 1) asm volatile("s_waitcnt vmcnt(4)" ::: "memory");
            else             asm volatile("s_waitcnt vmcnt(0)" ::: "memory");
            __builtin_amdgcn_sched_barrier(0);

            if (t + 2 < SEQ) {                // refill the buffer freed at t-1
                const int tok = __shfl(ytok, t + 2, 64);
                issue_matrix_load(core + (size_t)tok * RNK, mybuf + ((t + 2) % 3) * 1024, lane);
            }

            const float* M = mybuf + (t % 3) * 1024;   // LDS reads: bank = s -> 2-way, free
            float a0 = 0.f, a1 = 0.f, a2 = 0.f, a3 = 0.f;
            #pragma unroll
            for (int i = 0; i < 16; i += 4) {
                a0 = fmaf(__shfl(state, half * 16 + i + 0, 64), M[(half * 16 + i + 0) * 32 + s], a0);
                a1 = fmaf(__shfl(state, half * 16 + i + 1, 64), M[(half * 16 + i + 1) * 32 + s], a1);
                a2 = fmaf(__shfl(state, half * 16 + i + 2, 64), M[(half * 16 + i + 2) * 32 + s], a2);
                a3 = fmaf(__shfl(state, half * 16 + i + 3, 64), M[(half * 16 + i + 3) * 32 + s], a3);
            }
            const float acc = (a0 + a1) + (a2 + a3);
            state = acc + __shfl_xor(acc, 32, 64);     // combine halves, re-replicate
        }

        float p = state * betav;
        #pragma unroll
        for (int m = 16; m >= 1; m >>= 1) p += __shfl_xor(p, m, 64); // within-half sum
        if (lane == 0) out[row] = p;
    } else {
        // ---------------- reduce role: gm[r][s] += sum_v core[r][v][s] ----------------
        const int bid   = blockIdx.x - CHAIN_BLOCKS;
        const int r     = bid & 31;
        const int chunk = bid >> 5;           // 0..124
        const int tid   = threadIdx.x;

        const float4* slab = (const float4*)(core + (size_t)r * VOC * RNK);
        const int base = chunk * 2048 + tid;  // float4 index

        float a0 = 0.f, a1 = 0.f, a2 = 0.f, a3 = 0.f;
        #pragma unroll
        for (int i = 0; i < 8; ++i) {
            float4 v = slab[base + i * 256];
            a0 += v.x; a1 += v.y; a2 += v.z; a3 += v.w;
        }

        float* ml = shmem;                    // first 32 floats
        if (tid < RNK) ml[tid] = 0.f;
        __syncthreads();

        const int s0 = (tid & 7) * 4;         // (tid*4) % 32, loop-invariant phase
        atomicAdd(&ml[s0 + 0], a0);
        atomicAdd(&ml[s0 + 1], a1);
        atomicAdd(&ml[s0 + 2], a2);
        atomicAdd(&ml[s0 + 3], a3);
        __syncthreads();

        if (tid < RNK) atomicAdd(&gm[r * RNK + tid], ml[tid]);
    }
}

// ---------------------------------------------------------------------------
// z = alpha @ m^SEQ @ beta * BSZ  (single wave; runs after fused kernel)
// ---------------------------------------------------------------------------
__global__ void zchain_kernel(const float* __restrict__ gm,
                              const float* __restrict__ alpha,
                              const float* __restrict__ beta,
                              float* __restrict__ out) {
    const int lane = threadIdx.x & 63;
    const int s    = lane & 31;
    const int half = lane >> 5;

    float col[16];                            // this lane's half-column of m
    #pragma unroll
    for (int i = 0; i < 16; ++i) col[i] = gm[(half * 16 + i) * RNK + s];

    float v = alpha[s];
    #pragma unroll
    for (int t = 0; t < SEQ; ++t) {
        float a0 = 0.f, a1 = 0.f, a2 = 0.f, a3 = 0.f;
        #pragma unroll
        for (int i = 0; i < 16; i += 4) {
            a0 = fmaf(__shfl(v, half * 16 + i + 0, 64), col[i + 0], a0);
            a1 = fmaf(__shfl(v, half * 16 + i + 1, 64), col[i + 1], a1);
            a2 = fmaf(__shfl(v, half * 16 + i + 2, 64), col[i + 2], a2);
            a3 = fmaf(__shfl(v, half * 16 + i + 3, 64), col[i + 3], a3);
        }
        const float acc = (a0 + a1) + (a2 + a3);
        v = acc + __shfl_xor(acc, 32, 64);
    }
    float z = v * beta[s];
    #pragma unroll
    for (int m = 16; m >= 1; m >>= 1) z += __shfl_xor(z, m, 64);
    if (lane == 0) out[BSZ] = z * (float)BSZ;
}

extern "C" void kernel_launch(void* const* d_in, const int* in_sizes, int n_in,
                              void* d_out, int out_size, void* d_ws, size_t ws_size,
                              hipStream_t stream) {
    const int*   y     = (const int*)d_in[0];
    const float* alpha = (const float*)d_in[1];
    const float* beta  = (const float*)d_in[2];
    const float* core  = (const float*)d_in[3];
    float* out = (float*)d_out;
    float* gm  = (float*)d_ws;                // 1024 floats of scratch

    hipMemsetAsync(gm, 0, RNK * RNK * sizeof(float), stream);
    fused_kernel<<<CHAIN_BLOCKS + REDUCE_BLOCKS, 256, 0, stream>>>(core, y, alpha, beta, out, gm);
    zchain_kernel<<<1, 64, 0, stream>>>(gm, alpha, beta, out);
}

// Round 5
// 42.329 us; speedup vs baseline: 3.8865x; 1.1434x over previous
//
#include <hip/hip_runtime.h>

#define RNK 32
#define VOC 32000
#define BSZ 512
#define SEQ 24

#define BLOCK 128
#define CHAIN_BLOCKS 256          // 2 waves/block, 1 row per wave
#define REDUCE_BLOCKS 4000        // 32 r-slabs x 125 chunks of 2048 float4
#define DEPTH 6                   // tokens in flight per wave (6 x 4KB LDS)

typedef const __attribute__((address_space(1))) void* as1_cvp;
typedef __attribute__((address_space(3))) void* as3_vp;

// Issue one 32x32 fp32 token matrix (4 KB) global->LDS as 4 x (64 lanes x 16B).
// LDS dest is wave-uniform base (+ implicit lane*16, linear [r][s] layout);
// global src is per-lane: row r = j*8 + lane/8 (stride VOC*RNK), cols (lane%8)*4..+3.
__device__ __forceinline__ void issue_matrix_load(const float* src_tok, // core + tok*RNK
                                                  float* lds_base, int lane) {
    const int r  = lane >> 3;
    const int c0 = (lane & 7) * 4;
    #pragma unroll
    for (int j = 0; j < 4; ++j) {
        const float* src = src_tok + (size_t)(j * 8 + r) * ((size_t)VOC * RNK) + c0;
        __builtin_amdgcn_global_load_lds((as1_cvp)src, (as3_vp)(lds_base + j * 256), 16, 0, 0);
    }
}

// ---------------------------------------------------------------------------
// Fused kernel.
//  - Blocks [0, CHAIN_BLOCKS): selected-token chain. Depth-6 LDS pipeline via
//    global_load_lds + counted vmcnt (never 0 until the tail) hides gather
//    latency under the fma chain even while reduce saturates HBM.
//  - Blocks [CHAIN_BLOCKS, ...): stream core, build gm[r][s] = sum_v core.
// ---------------------------------------------------------------------------
__global__ __launch_bounds__(BLOCK) void fused_kernel(const float* __restrict__ core,
                                                      const int* __restrict__ y,
                                                      const float* __restrict__ alpha,
                                                      const float* __restrict__ beta,
                                                      float* __restrict__ out,
                                                      float* __restrict__ gm) {
    __shared__ float shmem[2 * DEPTH * 1024 + RNK];   // 48KB chain bufs (or reduce's ml)

    if (blockIdx.x < CHAIN_BLOCKS) {
        // ---------------- chain role: p_tilde[row] ----------------
        const int tid  = threadIdx.x;
        const int lane = tid & 63;
        const int w    = tid >> 6;            // wave 0..1, one row per wave
        const int s    = lane & 31;
        const int half = lane >> 5;           // 0: rows 0..15, 1: rows 16..31
        const int row  = blockIdx.x * 2 + w;

        float* mybuf = shmem + w * (DEPTH * 1024);    // private to this wave

        int   ytok  = (lane < SEQ) ? y[row * SEQ + lane] : 0;
        float state = alpha[s];               // replicated in both halves
        float betav = beta[s];

        // Drain scalar/vector loads so vmcnt counts ONLY our gl_lds ops.
        asm volatile("s_waitcnt vmcnt(0)" ::: "memory");

        // prologue: tokens 0..5 in flight (24 outstanding gl_lds)
        #pragma unroll
        for (int pt = 0; pt < DEPTH; ++pt) {
            const int tok = __shfl(ytok, pt, 64);
            issue_matrix_load(core + (size_t)tok * RNK, mybuf + pt * 1024, lane);
        }

        #pragma unroll
        for (int t = 0; t < SEQ; ++t) {       // fully unrolled -> waits are literals
            // token t's 4 loads complete; up to DEPTH-1 tokens stay in flight
            if      (t <= SEQ - DEPTH) asm volatile("s_waitcnt vmcnt(20)" ::: "memory");
            else if (t == SEQ - 5)     asm volatile("s_waitcnt vmcnt(16)" ::: "memory");
            else if (t == SEQ - 4)     asm volatile("s_waitcnt vmcnt(12)" ::: "memory");
            else if (t == SEQ - 3)     asm volatile("s_waitcnt vmcnt(8)"  ::: "memory");
            else if (t == SEQ - 2)     asm volatile("s_waitcnt vmcnt(4)"  ::: "memory");
            else                       asm volatile("s_waitcnt vmcnt(0)"  ::: "memory");
            __builtin_amdgcn_sched_barrier(0);

            if (t + DEPTH < SEQ) {            // refill the buffer just freed
                const int tok = __shfl(ytok, t + DEPTH, 64);
                issue_matrix_load(core + (size_t)tok * RNK,
                                  mybuf + ((t + DEPTH) % DEPTH) * 1024, lane);
            }

            const float* M = mybuf + (t % DEPTH) * 1024;  // bank = s -> 2-way (free)
            float a0 = 0.f, a1 = 0.f, a2 = 0.f, a3 = 0.f;
            #pragma unroll
            for (int i = 0; i < 16; i += 4) {
                a0 = fmaf(__shfl(state, half * 16 + i + 0, 64), M[(half * 16 + i + 0) * 32 + s], a0);
                a1 = fmaf(__shfl(state, half * 16 + i + 1, 64), M[(half * 16 + i + 1) * 32 + s], a1);
                a2 = fmaf(__shfl(state, half * 16 + i + 2, 64), M[(half * 16 + i + 2) * 32 + s], a2);
                a3 = fmaf(__shfl(state, half * 16 + i + 3, 64), M[(half * 16 + i + 3) * 32 + s], a3);
            }
            const float acc = (a0 + a1) + (a2 + a3);
            state = acc + __shfl_xor(acc, 32, 64);     // combine halves, re-replicate
        }

        float p = state * betav;
        #pragma unroll
        for (int m = 16; m >= 1; m >>= 1) p += __shfl_xor(p, m, 64); // within-half sum
        if (lane == 0) out[row] = p;
    } else {
        // ---------------- reduce role: gm[r][s] += sum_v core[r][v][s] ----------------
        const int bid   = blockIdx.x - CHAIN_BLOCKS;
        const int r     = bid & 31;
        const int chunk = bid >> 5;           // 0..124
        const int tid   = threadIdx.x;

        const float4* slab = (const float4*)(core + (size_t)r * VOC * RNK);
        const int base = chunk * 2048 + tid;  // float4 index

        float a0 = 0.f, a1 = 0.f, a2 = 0.f, a3 = 0.f;
        #pragma unroll
        for (int i = 0; i < 16; ++i) {
            float4 v = slab[base + i * 128];
            a0 += v.x; a1 += v.y; a2 += v.z; a3 += v.w;
        }

        float* ml = shmem;                    // first 32 floats
        if (tid < RNK) ml[tid] = 0.f;
        __syncthreads();

        const int s0 = (tid & 7) * 4;         // (tid*4) % 32, loop-invariant phase
        atomicAdd(&ml[s0 + 0], a0);
        atomicAdd(&ml[s0 + 1], a1);
        atomicAdd(&ml[s0 + 2], a2);
        atomicAdd(&ml[s0 + 3], a3);
        __syncthreads();

        if (tid < RNK) atomicAdd(&gm[r * RNK + tid], ml[tid]);
    }
}

// ---------------------------------------------------------------------------
// z = alpha @ m^SEQ @ beta * BSZ  (single wave; runs after fused kernel)
// ---------------------------------------------------------------------------
__global__ void zchain_kernel(const float* __restrict__ gm,
                              const float* __restrict__ alpha,
                              const float* __restrict__ beta,
                              float* __restrict__ out) {
    const int lane = threadIdx.x & 63;
    const int s    = lane & 31;
    const int half = lane >> 5;

    float col[16];                            // this lane's half-column of m
    #pragma unroll
    for (int i = 0; i < 16; ++i) col[i] = gm[(half * 16 + i) * RNK + s];

    float v = alpha[s];
    #pragma unroll
    for (int t = 0; t < SEQ; ++t) {
        float a0 = 0.f, a1 = 0.f, a2 = 0.f, a3 = 0.f;
        #pragma unroll
        for (int i = 0; i < 16; i += 4) {
            a0 = fmaf(__shfl(v, half * 16 + i + 0, 64), col[i + 0], a0);
            a1 = fmaf(__shfl(v, half * 16 + i + 1, 64), col[i + 1], a1);
            a2 = fmaf(__shfl(v, half * 16 + i + 2, 64), col[i + 2], a2);
            a3 = fmaf(__shfl(v, half * 16 + i + 3, 64), col[i + 3], a3);
        }
        const float acc = (a0 + a1) + (a2 + a3);
        v = acc + __shfl_xor(acc, 32, 64);
    }
    float z = v * beta[s];
    #pragma unroll
    for (int m = 16; m >= 1; m >>= 1) z += __shfl_xor(z, m, 64);
    if (lane == 0) out[BSZ] = z * (float)BSZ;
}

extern "C" void kernel_launch(void* const* d_in, const int* in_sizes, int n_in,
                              void* d_out, int out_size, void* d_ws, size_t ws_size,
                              hipStream_t stream) {
    const int*   y     = (const int*)d_in[0];
    const float* alpha = (const float*)d_in[1];
    const float* beta  = (const float*)d_in[2];
    const float* core  = (const float*)d_in[3];
    float* out = (float*)d_out;
    float* gm  = (float*)d_ws;                // 1024 floats of scratch

    hipMemsetAsync(gm, 0, RNK * RNK * sizeof(float), stream);
    fused_kernel<<<CHAIN_BLOCKS + REDUCE_BLOCKS, BLOCK, 0, stream>>>(core, y, alpha, beta, out, gm);
    zchain_kernel<<<1, 64, 0, stream>>>(gm, alpha, beta, out);
}